// Round 12
// baseline (593.525 us; speedup 1.0000x reference)
//
#include <hip/hip_runtime.h>

// ---------------------------------------------------------------------------
// KAN-GNN forward on MI355X.  Sizes (fixed by reference): N=100000 nodes,
// E=1600000 edges, IN=64, MID=5, HID=128, OUT=1, NG=512 graphs, C=11 basis.
// Round 12 (= round 11 fixed): non-temporal edge-list loads in count8/fill8.
// Round-10 counters showed FETCH 50MB + WRITE 73MB on fill8 = write-allocate
// RMW: the 12.8MB src/dst stream thrashes the partition's 800KB csr slice out
// of its XCD L2 before lines fill.  nt-hint the streaming reads so csr lines
// stay resident and write back full.  (Round-11 compile fix: the builtin
// needs a Clang ext_vector type, not HIP's int4 class -> int4v.)
// ---------------------------------------------------------------------------

#define IN_F   64
#define MID_F  5
#define HID_F  128
#define NG     512
#define NC     11   // G_GRID + K_SPLINE = 8 + 3
#define NJ     14   // intervals of [-1.75, 1.75) at h=0.25
#define NXCD   8

typedef __attribute__((ext_vector_type(8))) __bf16 bf16x8;
typedef __attribute__((ext_vector_type(4))) float  f32x4;
typedef __attribute__((ext_vector_type(4))) int    int4v;   // nt-load-able

// Cubic B-spline basis on uniform knots t_j = -1.75 + 0.25 j, j=0..14.
// (used by the tiny readout kernels)
__device__ __forceinline__ void bspline11(float x, float* __restrict__ B) {
    float b[14];
#pragma unroll
    for (int j = 0; j < 14; ++j) {
        float tj = -1.75f + 0.25f * j;
        b[j] = (x >= tj && x < tj + 0.25f) ? 1.0f : 0.0f;
    }
#pragma unroll
    for (int d = 1; d <= 3; ++d) {
        float inv = 1.0f / (0.25f * d);
#pragma unroll 14
        for (int j = 0; j < 14 - 3; ++j) {
            if (j < 14 - d) {
                float tj   = -1.75f + 0.25f * j;
                float tjd1 = tj + 0.25f * (d + 1);
                b[j] = ((x - tj) * b[j] + (tjd1 - x) * b[j + 1]) * inv;
            }
        }
        if (d < 3) {
#pragma unroll
            for (int j = 11; j < 14; ++j) {
                if (j < 14 - d) {
                    float tj   = -1.75f + 0.25f * j;
                    float tjd1 = tj + 0.25f * (d + 1);
                    b[j] = ((x - tj) * b[j] + (tjd1 - x) * b[j + 1]) * inv;
                }
            }
        }
    }
#pragma unroll
    for (int j = 0; j < NC; ++j) B[j] = b[j];
}

__device__ __forceinline__ float silu_f(float x) { return x / (1.0f + expf(-x)); }

// ---- build piecewise-cubic tables: poly[idx][4] = {a,b,c,d} in local u ----
__device__ __forceinline__ float4 poly_from_coefs(float c0, float c1, float c2, float c3) {
    const float s = 1.0f / 6.0f;
    float4 p;
    p.x = (-c0 + 3.f*c1 - 3.f*c2 + c3) * s;   // u^3
    p.y = ( 3.f*c0 - 6.f*c1 + 3.f*c2) * s;    // u^2
    p.z = (-3.f*c0 + 3.f*c2) * s;             // u^1
    p.w = (      c0 + 4.f*c1 + c2) * s;       // 1
    return p;
}

// poly1 layout: [i (64)][j (14)][o (5)][4]
__global__ __launch_bounds__(256) void build_poly1_kernel(
    const float* __restrict__ coef1, const float* __restrict__ ss1,
    float* __restrict__ poly1)
{
    int idx = blockIdx.x * 256 + threadIdx.x;
    if (idx >= IN_F * NJ * MID_F) return;
    int o = idx % MID_F;
    int t = idx / MID_F;
    int j = t % NJ;
    int i = t / NJ;
    float ss = ss1[i * MID_F + o];
    float c[4];
#pragma unroll
    for (int k = 0; k < 4; ++k) {
        int cc = j - 3 + k;
        c[k] = (cc >= 0 && cc <= 10) ? coef1[(i * MID_F + o) * NC + cc] * ss : 0.f;
    }
    *(float4*)(poly1 + (size_t)idx * 4) = poly_from_coefs(c[0], c[1], c[2], c[3]);
}

// poly2 layout: [i (5)][j (14)][o (128)][4]
__global__ __launch_bounds__(256) void build_poly2_kernel(
    const float* __restrict__ coef2, const float* __restrict__ ss2,
    float* __restrict__ poly2)
{
    int idx = blockIdx.x * 256 + threadIdx.x;
    if (idx >= MID_F * NJ * HID_F) return;
    int o = idx & 127;
    int t = idx >> 7;
    int j = t % NJ;
    int i = t / NJ;
    float ss = ss2[i * HID_F + o];
    float c[4];
#pragma unroll
    for (int k = 0; k < 4; ++k) {
        int cc = j - 3 + k;
        c[k] = (cc >= 0 && cc <= 10) ? coef2[(i * HID_F + o) * NC + cc] * ss : 0.f;
    }
    *(float4*)(poly2 + (size_t)idx * 4) = poly_from_coefs(c[0], c[1], c[2], c[3]);
}

// ---- repack [Ws;Wn] (K=256 x 128) into MFMA fragment order, bf16 ----------
__global__ __launch_bounds__(256) void build_wfrag_kernel(
    const float* __restrict__ Ws0, const float* __restrict__ Wn0,
    const float* __restrict__ Ws1, const float* __restrict__ Wn1,
    unsigned short* __restrict__ wfrag0, unsigned short* __restrict__ wfrag1)
{
    int t = blockIdx.x * 256 + threadIdx.x;
    if (t >= 2 * 256 * HID_F) return;
    int layer = t >> 15;
    int e = t & 32767;
    int col = e & 127;
    int k   = e >> 7;          // 0..255
    int ks  = k >> 5;
    int kin = k & 31;
    int lg  = kin >> 3;
    int j   = kin & 7;
    int c   = col >> 4;
    int li  = col & 15;
    int l   = lg * 16 + li;
    const float* Ws = layer ? Ws1 : Ws0;
    const float* Wn = layer ? Wn1 : Wn0;
    float v = (k < HID_F) ? Ws[k * HID_F + col] : Wn[(k - HID_F) * HID_F + col];
    unsigned short us = __builtin_bit_cast(unsigned short, (__bf16)v);
    unsigned short* dst = layer ? wfrag1 : wfrag0;
    dst[((ks * 8 + c) * 64 + l) * 8 + j] = us;
}

// -------------------- KAN encoder layer 1: [N,64] -> [N,5] -----------------
__global__ __launch_bounds__(256) void enc1_kernel(
    const float* __restrict__ h, const float* __restrict__ poly1,
    const float* __restrict__ sb1, float* __restrict__ mid, int N)
{
    __shared__ float s_sb[IN_F * MID_F];
    for (int idx = threadIdx.x; idx < IN_F * MID_F; idx += 256)
        s_sb[idx] = sb1[idx];
    __syncthreads();

    int n = blockIdx.x * 256 + threadIdx.x;
    if (n >= N) return;
    const float* hr = h + (size_t)n * IN_F;
    float acc[MID_F] = {0, 0, 0, 0, 0};

#pragma unroll 4
    for (int i4 = 0; i4 < IN_F; i4 += 4) {
        float4 xv = *(const float4*)(hr + i4);
        float xs[4] = {xv.x, xv.y, xv.z, xv.w};
#pragma unroll
        for (int k = 0; k < 4; ++k) {
            int i = i4 + k;
            float x = xs[k];
            float xf = (x + 1.75f) * 4.0f;
            float fj = floorf(xf);
            int j0 = (int)fj;
            j0 = j0 < 0 ? 0 : (j0 > 13 ? 13 : j0);
            float u = xf - fj;
            float msk = (x >= -1.75f && x < 1.75f) ? 1.0f : 0.0f;
            float s = silu_f(x);
            const float* pp = poly1 + ((size_t)(i * NJ + j0) * MID_F) * 4;
#pragma unroll
            for (int o = 0; o < MID_F; ++o) {
                float4 p = *(const float4*)(pp + 4 * o);
                float t = fmaf(fmaf(fmaf(p.x, u, p.y), u, p.z), u, p.w);
                acc[o] = fmaf(s_sb[i * MID_F + o], s, acc[o]);
                acc[o] = fmaf(t, msk, acc[o]);
            }
        }
    }
#pragma unroll
    for (int o = 0; o < MID_F; ++o) mid[(size_t)n * MID_F + o] = acc[o];
}

// ------------- KAN encoder layer 2: [N,5] -> [N,128] (+ bf16 shadow) -------
__global__ __launch_bounds__(256) void enc2_kernel(
    const float* __restrict__ mid, const float* __restrict__ poly2,
    const float* __restrict__ sb2, float* __restrict__ h0,
    unsigned short* __restrict__ hb, int N)
{
    __shared__ float s_u[2][MID_F], s_sil[2][MID_F], s_msk[2][MID_F];
    __shared__ int   s_j0[2][MID_F];
    int o  = threadIdx.x & 127;
    int ln = threadIdx.x >> 7;

    float sbr[MID_F];
#pragma unroll
    for (int i = 0; i < MID_F; ++i) sbr[i] = sb2[i * HID_F + o];

    int nTiles = (N + 1) / 2;
    for (int tile = blockIdx.x; tile < nTiles; tile += gridDim.x) {
        __syncthreads();
        if (threadIdx.x < 2 * MID_F) {
            int l = threadIdx.x / MID_F, i = threadIdx.x % MID_F;
            int n = tile * 2 + l;
            float x = (n < N) ? mid[(size_t)n * MID_F + i] : 0.f;
            float xf = (x + 1.75f) * 4.0f;
            float fj = floorf(xf);
            int j0 = (int)fj;
            j0 = j0 < 0 ? 0 : (j0 > 13 ? 13 : j0);
            s_j0[l][i]  = j0;
            s_u[l][i]   = xf - fj;
            s_msk[l][i] = (x >= -1.75f && x < 1.75f) ? 1.0f : 0.0f;
            s_sil[l][i] = silu_f(x);
        }
        __syncthreads();
        int n = tile * 2 + ln;
        if (n < N) {
            float z = 0.f;
#pragma unroll
            for (int i = 0; i < MID_F; ++i) {
                float4 p = *(const float4*)(poly2 +
                            ((size_t)((i * NJ + s_j0[ln][i]) * HID_F + o)) * 4);
                float u = s_u[ln][i];
                float t = fmaf(fmaf(fmaf(p.x, u, p.y), u, p.z), u, p.w);
                z = fmaf(sbr[i], s_sil[ln][i], z);
                z = fmaf(t, s_msk[ln][i], z);
            }
            h0[(size_t)n * HID_F + o] = z;
            hb[(size_t)n * HID_F + o] =
                __builtin_bit_cast(unsigned short, (__bf16)z);
        }
    }
}

// --------- CSR build, XCD-partitioned + nt streaming reads -----------------
__global__ __launch_bounds__(256) void count8_kernel(
    const int* __restrict__ dst, int* __restrict__ cnt, int E, int psz)
{
    int part = blockIdx.x & (NXCD - 1);
    int blk  = blockIdx.x >> 3;
    int plo = part * psz, phi = plo + psz;
    int e0 = (blk * 256 + threadIdx.x) * 4;
    if (e0 >= E) return;
    if (e0 + 3 < E) {
        int4v d4 = __builtin_nontemporal_load((const int4v*)(dst + e0));
        if (d4.x >= plo && d4.x < phi) atomicAdd(&cnt[d4.x], 1);
        if (d4.y >= plo && d4.y < phi) atomicAdd(&cnt[d4.y], 1);
        if (d4.z >= plo && d4.z < phi) atomicAdd(&cnt[d4.z], 1);
        if (d4.w >= plo && d4.w < phi) atomicAdd(&cnt[d4.w], 1);
    } else {
        for (int k = 0; k < 4 && e0 + k < E; ++k) {
            int d = dst[e0 + k];
            if (d >= plo && d < phi) atomicAdd(&cnt[d], 1);
        }
    }
}

__global__ __launch_bounds__(256) void scan1_kernel(
    const int* __restrict__ cnt, int* __restrict__ offs,
    int* __restrict__ bsum, int N)
{
    __shared__ int s[256];
    int base = blockIdx.x * 1024 + threadIdx.x * 4;
    int v0 = (base + 0 < N) ? cnt[base + 0] : 0;
    int v1 = (base + 1 < N) ? cnt[base + 1] : 0;
    int v2 = (base + 2 < N) ? cnt[base + 2] : 0;
    int v3 = (base + 3 < N) ? cnt[base + 3] : 0;
    int tsum = v0 + v1 + v2 + v3;
    s[threadIdx.x] = tsum;
    __syncthreads();
    for (int off = 1; off < 256; off <<= 1) {
        int t = 0;
        if (threadIdx.x >= off) t = s[threadIdx.x - off];
        __syncthreads();
        if (threadIdx.x >= off) s[threadIdx.x] += t;
        __syncthreads();
    }
    int p = s[threadIdx.x] - tsum;
    if (threadIdx.x == 255) bsum[blockIdx.x] = s[255];
    if (base + 0 < N) { offs[base + 0] = p; p += v0; }
    if (base + 1 < N) { offs[base + 1] = p; p += v1; }
    if (base + 2 < N) { offs[base + 2] = p; p += v2; }
    if (base + 3 < N) { offs[base + 3] = p; p += v3; }
}

__global__ __launch_bounds__(256) void scan2_kernel(int* __restrict__ bsum, int nblk)
{
    __shared__ int s[256];
    int v = (threadIdx.x < nblk) ? bsum[threadIdx.x] : 0;
    s[threadIdx.x] = v;
    __syncthreads();
    for (int off = 1; off < 256; off <<= 1) {
        int t = 0;
        if (threadIdx.x >= off) t = s[threadIdx.x - off];
        __syncthreads();
        if (threadIdx.x >= off) s[threadIdx.x] += t;
        __syncthreads();
    }
    if (threadIdx.x < nblk) bsum[threadIdx.x] = s[threadIdx.x] - v;
}

__global__ __launch_bounds__(256) void scan3_kernel(
    int* __restrict__ offs, const int* __restrict__ bsum, int N, int E)
{
    int i = blockIdx.x * 256 + threadIdx.x;
    if (i < N) offs[i] += bsum[i >> 10];
    if (i == 0) offs[N] = E;
}

__global__ __launch_bounds__(256) void fill8_kernel(
    const int* __restrict__ src, const int* __restrict__ dst,
    const int* __restrict__ offs, int* __restrict__ cursor,
    int* __restrict__ csr, int E, int psz)
{
    int part = blockIdx.x & (NXCD - 1);
    int blk  = blockIdx.x >> 3;
    int plo = part * psz, phi = plo + psz;
    int e0 = (blk * 256 + threadIdx.x) * 4;
    if (e0 >= E) return;
    if (e0 + 3 < E) {
        int4v d4 = __builtin_nontemporal_load((const int4v*)(dst + e0));
        int4v s4 = __builtin_nontemporal_load((const int4v*)(src + e0));
        if (d4.x >= plo && d4.x < phi) { int p = atomicAdd(&cursor[d4.x], 1); csr[offs[d4.x] + p] = s4.x; }
        if (d4.y >= plo && d4.y < phi) { int p = atomicAdd(&cursor[d4.y], 1); csr[offs[d4.y] + p] = s4.y; }
        if (d4.z >= plo && d4.z < phi) { int p = atomicAdd(&cursor[d4.z], 1); csr[offs[d4.z] + p] = s4.z; }
        if (d4.w >= plo && d4.w < phi) { int p = atomicAdd(&cursor[d4.w], 1); csr[offs[d4.w] + p] = s4.w; }
    } else {
        for (int k = 0; k < 4 && e0 + k < E; ++k) {
            int d = dst[e0 + k];
            if (d >= plo && d < phi) {
                int p = atomicAdd(&cursor[d], 1);
                csr[offs[d] + p] = src[e0 + k];
            }
        }
    }
}

// ---------- gather aggregation (bf16 rows): mean over in-neighbors ---------
// one wave per node; lane l owns features [2l, 2l+1] (one dword of hb row)
__global__ __launch_bounds__(256) void agg_kernel(
    const unsigned short* __restrict__ hb, const int* __restrict__ csr,
    const int* __restrict__ offs, unsigned short* __restrict__ meanb, int N)
{
    int wid  = (blockIdx.x * 256 + threadIdx.x) >> 6;   // node id
    int lane = threadIdx.x & 63;
    if (wid >= N) return;
    int lo = offs[wid], hi = offs[wid + 1];
    float ax = 0.f, ay = 0.f;
    for (int base = lo; base < hi; base += 64) {
        int m = hi - base;
        int idx = 0;
        if (lane < m) idx = csr[base + lane];
        int cnt = m < 64 ? m : 64;
        int j = 0;
        for (; j + 3 < cnt; j += 4) {
            int s0 = __shfl(idx, j + 0);
            int s1 = __shfl(idx, j + 1);
            int s2 = __shfl(idx, j + 2);
            int s3 = __shfl(idx, j + 3);
            unsigned int v0 = *(const unsigned int*)(hb + (size_t)s0 * HID_F + lane * 2);
            unsigned int v1 = *(const unsigned int*)(hb + (size_t)s1 * HID_F + lane * 2);
            unsigned int v2 = *(const unsigned int*)(hb + (size_t)s2 * HID_F + lane * 2);
            unsigned int v3 = *(const unsigned int*)(hb + (size_t)s3 * HID_F + lane * 2);
            ax += __builtin_bit_cast(float, v0 << 16) + __builtin_bit_cast(float, v1 << 16)
                + __builtin_bit_cast(float, v2 << 16) + __builtin_bit_cast(float, v3 << 16);
            ay += __builtin_bit_cast(float, v0 & 0xffff0000u) + __builtin_bit_cast(float, v1 & 0xffff0000u)
                + __builtin_bit_cast(float, v2 & 0xffff0000u) + __builtin_bit_cast(float, v3 & 0xffff0000u);
        }
        for (; j < cnt; ++j) {
            int s0 = __shfl(idx, j);
            unsigned int v0 = *(const unsigned int*)(hb + (size_t)s0 * HID_F + lane * 2);
            ax += __builtin_bit_cast(float, v0 << 16);
            ay += __builtin_bit_cast(float, v0 & 0xffff0000u);
        }
    }
    float inv = (hi > lo) ? 1.0f / (float)(hi - lo) : 0.0f;
    unsigned short ux = __builtin_bit_cast(unsigned short, (__bf16)(ax * inv));
    unsigned short uy = __builtin_bit_cast(unsigned short, (__bf16)(ay * inv));
    *(unsigned int*)(meanb + (size_t)wid * HID_F + lane * 2) =
        (unsigned int)ux | ((unsigned int)uy << 16);
}

// -------------------- SAGE update via MFMA ---------------------------------
// z = [hb|meanb](bf16) @ wfrag(bf16, K=256) + bias + hres (fp32); leaky.
__global__ __launch_bounds__(256) void sage_mfma_kernel(
    const unsigned short* __restrict__ hb, const unsigned short* __restrict__ meanb,
    const float* __restrict__ hres, const unsigned short* __restrict__ wfrag,
    const float* __restrict__ bias, float* __restrict__ hout,
    unsigned short* __restrict__ hbout, int N)
{
    int wv = threadIdx.x >> 6;
    int l  = threadIdx.x & 63;
    int n0 = blockIdx.x * 64 + wv * 16;
    int r  = l & 15;
    int kg = l >> 4;                          // 0..3

    const uint4* rowh = (const uint4*)(hb    + (size_t)(n0 + r) * HID_F);
    const uint4* rowm = (const uint4*)(meanb + (size_t)(n0 + r) * HID_F);
    const uint4* wp   = (const uint4*)wfrag + l;

    f32x4 acc[8] = {};
#pragma unroll
    for (int ks = 0; ks < 8; ++ks) {
        uint4 av = (ks < 4) ? rowh[ks * 4 + kg] : rowm[(ks - 4) * 4 + kg];
        bf16x8 a = __builtin_bit_cast(bf16x8, av);
#pragma unroll
        for (int c = 0; c < 8; ++c) {
            uint4 w = wp[(ks * 8 + c) * 64];
            bf16x8 b = __builtin_bit_cast(bf16x8, w);
            acc[c] = __builtin_amdgcn_mfma_f32_16x16x32_bf16(a, b, acc[c], 0, 0, 0);
        }
    }

    // epilogue: D[row=(l>>4)*4+rr][col=c*16+(l&15)]
    int row0 = kg * 4;
#pragma unroll
    for (int c = 0; c < 8; ++c) {
        int col = c * 16 + r;
        float bv = bias[col];
#pragma unroll
        for (int rr = 0; rr < 4; ++rr) {
            int grow = n0 + row0 + rr;
            if (grow < N) {
                float z = acc[c][rr] + bv + hres[(size_t)grow * HID_F + col];
                z = z > 0.f ? z : 0.01f * z;
                hout[(size_t)grow * HID_F + col] = z;
                if (hbout)
                    hbout[(size_t)grow * HID_F + col] =
                        __builtin_bit_cast(unsigned short, (__bf16)z);
            }
        }
    }
}

// ------------- fused graph-mean pool + KAN readout layer 1 ------------------
// 512 threads: 16-row x float4 parallel pooling -> LDS combine -> 128-thread
// KAN epilogue (thread i owns pooled feature i).
__global__ __launch_bounds__(512) void pool_readout1_kernel(
    const float* __restrict__ h, const int* __restrict__ gid,
    const float* __restrict__ coefr1, const float* __restrict__ sbr1,
    const float* __restrict__ ssr1, float* __restrict__ ymid, int N)
{
    int g = blockIdx.x;
    int tid = threadIdx.x;
    __shared__ int s_lo, s_hi;
    if (tid == 0) {
        int lo = 0, hi = N;
        while (lo < hi) { int m = (lo + hi) >> 1; if (gid[m] < g) lo = m + 1; else hi = m; }
        s_lo = lo;
        int lo2 = lo, hi2 = N;
        while (lo2 < hi2) { int m = (lo2 + hi2) >> 1; if (gid[m] < g + 1) lo2 = m + 1; else hi2 = m; }
        s_hi = lo2;
    }
    __syncthreads();
    int lo = s_lo, hi = s_hi;

    // parallel pooling: row-group ro = tid>>5 (16 rows in flight), cols c4..c4+3
    int ro = tid >> 5;
    int c4 = (tid & 31) * 4;
    float4 a = {0.f, 0.f, 0.f, 0.f};
    for (int n = lo + ro; n < hi; n += 16) {
        float4 v = *(const float4*)(h + (size_t)n * HID_F + c4);
        a.x += v.x; a.y += v.y; a.z += v.z; a.w += v.w;
    }
    __shared__ float s_acc[16][HID_F];   // 8 KB
    *(float4*)(&s_acc[ro][c4]) = a;
    __syncthreads();

    // KAN epilogue on first 128 threads (thread i owns feature i)
    __shared__ float s_part[2][MID_F];
    float p[MID_F];
    int i = tid;
    if (tid < HID_F) {
        float acc = 0.f;
#pragma unroll
        for (int r = 0; r < 16; ++r) acc += s_acc[r][i];
        float x = acc * (1.0f / fmaxf((float)(hi - lo), 1.0f));

        float B[NC];
        bspline11(x, B);
        float s = silu_f(x);
        const float* cp  = coefr1 + (size_t)i * (MID_F * NC);
        const float* ssp = ssr1 + (size_t)i * MID_F;
        const float* sbp = sbr1 + (size_t)i * MID_F;
#pragma unroll
        for (int o = 0; o < MID_F; ++o) {
            float t = 0.f;
#pragma unroll
            for (int c = 0; c < NC; ++c) t = fmaf(cp[o * NC + c], B[c], t);
            p[o] = sbp[o] * s + ssp[o] * t;
        }
#pragma unroll
        for (int off = 32; off >= 1; off >>= 1) {
#pragma unroll
            for (int o = 0; o < MID_F; ++o) p[o] += __shfl_down(p[o], off);
        }
        int lane = tid & 63, w = tid >> 6;
        if (lane == 0) {
#pragma unroll
            for (int o = 0; o < MID_F; ++o) s_part[w][o] = p[o];
        }
    }
    __syncthreads();
    if (tid < MID_F)
        ymid[g * MID_F + tid] = s_part[0][tid] + s_part[1][tid];
}

// -------------------- KAN readout layer 2 + sigmoid: [512,5] -> [512,1] ----
__global__ __launch_bounds__(256) void readout2_kernel(
    const float* __restrict__ ymid, const float* __restrict__ coefr2,
    const float* __restrict__ sbr2, const float* __restrict__ ssr2,
    float* __restrict__ out)
{
    int g = blockIdx.x * 256 + threadIdx.x;
    if (g >= NG) return;
    float acc = 0.f;
#pragma unroll
    for (int i = 0; i < MID_F; ++i) {
        float x = ymid[g * MID_F + i];
        float B[NC];
        bspline11(x, B);
        float t = 0.f;
#pragma unroll
        for (int c = 0; c < NC; ++c) t = fmaf(coefr2[i * NC + c], B[c], t);
        acc += sbr2[i] * silu_f(x) + ssr2[i] * t;
    }
    out[g] = 1.0f / (1.0f + expf(-acc));
}

// ---------------------------------------------------------------------------
extern "C" void kernel_launch(void* const* d_in, const int* in_sizes, int n_in,
                              void* d_out, int out_size, void* d_ws, size_t ws_size,
                              hipStream_t stream)
{
    const float* h     = (const float*)d_in[0];
    const int*   src   = (const int*)d_in[1];
    const int*   dst   = (const int*)d_in[2];
    const int*   gid   = (const int*)d_in[3];
    const float* coef1 = (const float*)d_in[4];
    const float* sb1   = (const float*)d_in[5];
    const float* ss1   = (const float*)d_in[6];
    const float* coef2 = (const float*)d_in[7];
    const float* sb2   = (const float*)d_in[8];
    const float* ss2   = (const float*)d_in[9];
    const float* Ws0   = (const float*)d_in[10];
    const float* Wn0   = (const float*)d_in[11];
    const float* b0    = (const float*)d_in[12];
    const float* Ws1   = (const float*)d_in[13];
    const float* Wn1   = (const float*)d_in[14];
    const float* b1    = (const float*)d_in[15];
    const float* coefr1= (const float*)d_in[16];
    const float* sbr1  = (const float*)d_in[17];
    const float* ssr1  = (const float*)d_in[18];
    const float* coefr2= (const float*)d_in[19];
    const float* sbr2  = (const float*)d_in[20];
    const float* ssr2  = (const float*)d_in[21];

    const int N = in_sizes[0] / IN_F;   // 100000
    const int E = in_sizes[1];          // 1600000

    // ---- workspace layout (same total footprint as round 10) ----
    float* ws   = (float*)d_ws;
    float* mid  = ws;                                   // N*5 f32
    float* h0   = mid + (size_t)N * MID_F;              // N*128 f32
    float* h1   = h0 + (size_t)N * HID_F;               // N*128 f32
    unsigned short* meanb = (unsigned short*)(h1 + (size_t)N * HID_F);  // N*128 bf16
    unsigned short* hb    = meanb + (size_t)N * HID_F;                  // N*128 bf16
    float* ymid = (float*)(hb + (size_t)N * HID_F);     // 512*5 f32
    unsigned short* wfrag0 = (unsigned short*)(ymid + NG * MID_F);  // 32768 us
    unsigned short* wfrag1 = wfrag0 + 32768;                        // 32768 us
    int*   cnt  = (int*)(wfrag1 + 32768);               // N (reused as cursor)
    int*   offs = cnt + N;                              // N+1
    int*   bsum = offs + N + 1;                         // 256
    int*   csr  = bsum + 256;                           // E

    // poly tables aliased onto meanb (dead until agg0 writes meanb):
    float* poly1 = (float*)meanb;                       // 64*14*5*4  = 17920 f32
    float* poly2 = poly1 + IN_F * NJ * MID_F * 4;       // 5*14*128*4 = 35840 f32

    const int nblk = (N + 1023) / 1024;
    const int psz  = (N + NXCD - 1) / NXCD;             // 12500
    const int ngrid8 = NXCD * ((E + 256 * 4 - 1) / (256 * 4));

    // build spline polynomial tables + bf16 weight fragment tables
    build_poly1_kernel<<<(IN_F * NJ * MID_F + 255) / 256, 256, 0, stream>>>(coef1, ss1, poly1);
    build_poly2_kernel<<<(MID_F * NJ * HID_F + 255) / 256, 256, 0, stream>>>(coef2, ss2, poly2);
    build_wfrag_kernel<<<(2 * 256 * HID_F + 255) / 256, 256, 0, stream>>>(
        Ws0, Wn0, Ws1, Wn1, wfrag0, wfrag1);

    // KAN encoder
    enc1_kernel<<<(N + 255) / 256, 256, 0, stream>>>(h, poly1, sb1, mid, N);
    enc2_kernel<<<2048, 256, 0, stream>>>(mid, poly2, sb2, h0, hb, N);

    // CSR build (once; reused by both SAGE layers), XCD-partitioned + nt
    hipMemsetAsync(cnt, 0, (size_t)N * sizeof(int), stream);
    count8_kernel<<<ngrid8, 256, 0, stream>>>(dst, cnt, E, psz);
    scan1_kernel<<<nblk, 256, 0, stream>>>(cnt, offs, bsum, N);
    scan2_kernel<<<1, 256, 0, stream>>>(bsum, nblk);
    scan3_kernel<<<(N + 255) / 256, 256, 0, stream>>>(offs, bsum, N, E);
    hipMemsetAsync(cnt, 0, (size_t)N * sizeof(int), stream);   // cnt -> cursor
    fill8_kernel<<<ngrid8, 256, 0, stream>>>(src, dst, offs, cnt, csr, E, psz);

    // SAGE layer 0: agg from hb -> meanb; GEMM; writes h1 + hb (in place)
    agg_kernel<<<(N * 64 + 255) / 256, 256, 0, stream>>>(hb, csr, offs, meanb, N);
    sage_mfma_kernel<<<(N + 63) / 64, 256, 0, stream>>>(
        hb, meanb, h0, wfrag0, b0, h1, hb, N);

    // SAGE layer 1: output bf16 shadow not needed (pool uses fp32)
    agg_kernel<<<(N * 64 + 255) / 256, 256, 0, stream>>>(hb, csr, offs, meanb, N);
    sage_mfma_kernel<<<(N + 63) / 64, 256, 0, stream>>>(
        hb, meanb, h1, wfrag1, b1, h0, (unsigned short*)nullptr, N);

    // fused pool + readout
    pool_readout1_kernel<<<NG, 512, 0, stream>>>(h0, gid, coefr1, sbr1, ssr1, ymid, N);
    readout2_kernel<<<2, 256, 0, stream>>>(ymid, coefr2, sbr2, ssr2, (float*)d_out);
}

// Round 14
// 589.851 us; speedup vs baseline: 1.0062x; 1.0062x over previous
//
#include <hip/hip_runtime.h>

// ---------------------------------------------------------------------------
// KAN-GNN forward on MI355X.  Sizes (fixed by reference): N=100000 nodes,
// E=1600000 edges, IN=64, MID=5, HID=128, OUT=1, NG=512 graphs, C=11 basis.
// Round 13 (resubmit; bench hit GPUAcquisitionTimeout): persistent
// co-resident CSR build.  Round-12 falsified the L2-stream-thrash theory
// (nt loads: WRITE 73->67MB only).  Revised theory: blockIdx&7 -> XCD
// round-robin binding DECAYS as 12504 blocks retire out of order and get
// backfilled onto any free XCD -> csr lines written from multiple
// non-coherent L2s -> partial-line writebacks.  Fix: exactly 1024 blocks
// (4/CU, all co-resident at t=0 so the initial round-robin mapping can
// never decay), grid-striding the edge list.  nt loads reverted.
// ---------------------------------------------------------------------------

#define IN_F   64
#define MID_F  5
#define HID_F  128
#define NG     512
#define NC     11   // G_GRID + K_SPLINE = 8 + 3
#define NJ     14   // intervals of [-1.75, 1.75) at h=0.25
#define NXCD   8
#define PGRID  1024  // persistent blocks: 8 partitions x 128, 4/CU co-resident

typedef __attribute__((ext_vector_type(8))) __bf16 bf16x8;
typedef __attribute__((ext_vector_type(4))) float  f32x4;

// Cubic B-spline basis on uniform knots t_j = -1.75 + 0.25 j, j=0..14.
// (used by the tiny readout kernels)
__device__ __forceinline__ void bspline11(float x, float* __restrict__ B) {
    float b[14];
#pragma unroll
    for (int j = 0; j < 14; ++j) {
        float tj = -1.75f + 0.25f * j;
        b[j] = (x >= tj && x < tj + 0.25f) ? 1.0f : 0.0f;
    }
#pragma unroll
    for (int d = 1; d <= 3; ++d) {
        float inv = 1.0f / (0.25f * d);
#pragma unroll 14
        for (int j = 0; j < 14 - 3; ++j) {
            if (j < 14 - d) {
                float tj   = -1.75f + 0.25f * j;
                float tjd1 = tj + 0.25f * (d + 1);
                b[j] = ((x - tj) * b[j] + (tjd1 - x) * b[j + 1]) * inv;
            }
        }
        if (d < 3) {
#pragma unroll
            for (int j = 11; j < 14; ++j) {
                if (j < 14 - d) {
                    float tj   = -1.75f + 0.25f * j;
                    float tjd1 = tj + 0.25f * (d + 1);
                    b[j] = ((x - tj) * b[j] + (tjd1 - x) * b[j + 1]) * inv;
                }
            }
        }
    }
#pragma unroll
    for (int j = 0; j < NC; ++j) B[j] = b[j];
}

__device__ __forceinline__ float silu_f(float x) { return x / (1.0f + expf(-x)); }

// ---- build piecewise-cubic tables: poly[idx][4] = {a,b,c,d} in local u ----
__device__ __forceinline__ float4 poly_from_coefs(float c0, float c1, float c2, float c3) {
    const float s = 1.0f / 6.0f;
    float4 p;
    p.x = (-c0 + 3.f*c1 - 3.f*c2 + c3) * s;   // u^3
    p.y = ( 3.f*c0 - 6.f*c1 + 3.f*c2) * s;    // u^2
    p.z = (-3.f*c0 + 3.f*c2) * s;             // u^1
    p.w = (      c0 + 4.f*c1 + c2) * s;       // 1
    return p;
}

// poly1 layout: [i (64)][j (14)][o (5)][4]
__global__ __launch_bounds__(256) void build_poly1_kernel(
    const float* __restrict__ coef1, const float* __restrict__ ss1,
    float* __restrict__ poly1)
{
    int idx = blockIdx.x * 256 + threadIdx.x;
    if (idx >= IN_F * NJ * MID_F) return;
    int o = idx % MID_F;
    int t = idx / MID_F;
    int j = t % NJ;
    int i = t / NJ;
    float ss = ss1[i * MID_F + o];
    float c[4];
#pragma unroll
    for (int k = 0; k < 4; ++k) {
        int cc = j - 3 + k;
        c[k] = (cc >= 0 && cc <= 10) ? coef1[(i * MID_F + o) * NC + cc] * ss : 0.f;
    }
    *(float4*)(poly1 + (size_t)idx * 4) = poly_from_coefs(c[0], c[1], c[2], c[3]);
}

// poly2 layout: [i (5)][j (14)][o (128)][4]
__global__ __launch_bounds__(256) void build_poly2_kernel(
    const float* __restrict__ coef2, const float* __restrict__ ss2,
    float* __restrict__ poly2)
{
    int idx = blockIdx.x * 256 + threadIdx.x;
    if (idx >= MID_F * NJ * HID_F) return;
    int o = idx & 127;
    int t = idx >> 7;
    int j = t % NJ;
    int i = t / NJ;
    float ss = ss2[i * HID_F + o];
    float c[4];
#pragma unroll
    for (int k = 0; k < 4; ++k) {
        int cc = j - 3 + k;
        c[k] = (cc >= 0 && cc <= 10) ? coef2[(i * HID_F + o) * NC + cc] * ss : 0.f;
    }
    *(float4*)(poly2 + (size_t)idx * 4) = poly_from_coefs(c[0], c[1], c[2], c[3]);
}

// ---- repack [Ws;Wn] (K=256 x 128) into MFMA fragment order, bf16 ----------
__global__ __launch_bounds__(256) void build_wfrag_kernel(
    const float* __restrict__ Ws0, const float* __restrict__ Wn0,
    const float* __restrict__ Ws1, const float* __restrict__ Wn1,
    unsigned short* __restrict__ wfrag0, unsigned short* __restrict__ wfrag1)
{
    int t = blockIdx.x * 256 + threadIdx.x;
    if (t >= 2 * 256 * HID_F) return;
    int layer = t >> 15;
    int e = t & 32767;
    int col = e & 127;
    int k   = e >> 7;          // 0..255
    int ks  = k >> 5;
    int kin = k & 31;
    int lg  = kin >> 3;
    int j   = kin & 7;
    int c   = col >> 4;
    int li  = col & 15;
    int l   = lg * 16 + li;
    const float* Ws = layer ? Ws1 : Ws0;
    const float* Wn = layer ? Wn1 : Wn0;
    float v = (k < HID_F) ? Ws[k * HID_F + col] : Wn[(k - HID_F) * HID_F + col];
    unsigned short us = __builtin_bit_cast(unsigned short, (__bf16)v);
    unsigned short* dst = layer ? wfrag1 : wfrag0;
    dst[((ks * 8 + c) * 64 + l) * 8 + j] = us;
}

// -------------------- KAN encoder layer 1: [N,64] -> [N,5] -----------------
__global__ __launch_bounds__(256) void enc1_kernel(
    const float* __restrict__ h, const float* __restrict__ poly1,
    const float* __restrict__ sb1, float* __restrict__ mid, int N)
{
    __shared__ float s_sb[IN_F * MID_F];
    for (int idx = threadIdx.x; idx < IN_F * MID_F; idx += 256)
        s_sb[idx] = sb1[idx];
    __syncthreads();

    int n = blockIdx.x * 256 + threadIdx.x;
    if (n >= N) return;
    const float* hr = h + (size_t)n * IN_F;
    float acc[MID_F] = {0, 0, 0, 0, 0};

#pragma unroll 4
    for (int i4 = 0; i4 < IN_F; i4 += 4) {
        float4 xv = *(const float4*)(hr + i4);
        float xs[4] = {xv.x, xv.y, xv.z, xv.w};
#pragma unroll
        for (int k = 0; k < 4; ++k) {
            int i = i4 + k;
            float x = xs[k];
            float xf = (x + 1.75f) * 4.0f;
            float fj = floorf(xf);
            int j0 = (int)fj;
            j0 = j0 < 0 ? 0 : (j0 > 13 ? 13 : j0);
            float u = xf - fj;
            float msk = (x >= -1.75f && x < 1.75f) ? 1.0f : 0.0f;
            float s = silu_f(x);
            const float* pp = poly1 + ((size_t)(i * NJ + j0) * MID_F) * 4;
#pragma unroll
            for (int o = 0; o < MID_F; ++o) {
                float4 p = *(const float4*)(pp + 4 * o);
                float t = fmaf(fmaf(fmaf(p.x, u, p.y), u, p.z), u, p.w);
                acc[o] = fmaf(s_sb[i * MID_F + o], s, acc[o]);
                acc[o] = fmaf(t, msk, acc[o]);
            }
        }
    }
#pragma unroll
    for (int o = 0; o < MID_F; ++o) mid[(size_t)n * MID_F + o] = acc[o];
}

// ------------- KAN encoder layer 2: [N,5] -> [N,128] (+ bf16 shadow) -------
__global__ __launch_bounds__(256) void enc2_kernel(
    const float* __restrict__ mid, const float* __restrict__ poly2,
    const float* __restrict__ sb2, float* __restrict__ h0,
    unsigned short* __restrict__ hb, int N)
{
    __shared__ float s_u[2][MID_F], s_sil[2][MID_F], s_msk[2][MID_F];
    __shared__ int   s_j0[2][MID_F];
    int o  = threadIdx.x & 127;
    int ln = threadIdx.x >> 7;

    float sbr[MID_F];
#pragma unroll
    for (int i = 0; i < MID_F; ++i) sbr[i] = sb2[i * HID_F + o];

    int nTiles = (N + 1) / 2;
    for (int tile = blockIdx.x; tile < nTiles; tile += gridDim.x) {
        __syncthreads();
        if (threadIdx.x < 2 * MID_F) {
            int l = threadIdx.x / MID_F, i = threadIdx.x % MID_F;
            int n = tile * 2 + l;
            float x = (n < N) ? mid[(size_t)n * MID_F + i] : 0.f;
            float xf = (x + 1.75f) * 4.0f;
            float fj = floorf(xf);
            int j0 = (int)fj;
            j0 = j0 < 0 ? 0 : (j0 > 13 ? 13 : j0);
            s_j0[l][i]  = j0;
            s_u[l][i]   = xf - fj;
            s_msk[l][i] = (x >= -1.75f && x < 1.75f) ? 1.0f : 0.0f;
            s_sil[l][i] = silu_f(x);
        }
        __syncthreads();
        int n = tile * 2 + ln;
        if (n < N) {
            float z = 0.f;
#pragma unroll
            for (int i = 0; i < MID_F; ++i) {
                float4 p = *(const float4*)(poly2 +
                            ((size_t)((i * NJ + s_j0[ln][i]) * HID_F + o)) * 4);
                float u = s_u[ln][i];
                float t = fmaf(fmaf(fmaf(p.x, u, p.y), u, p.z), u, p.w);
                z = fmaf(sbr[i], s_sil[ln][i], z);
                z = fmaf(t, s_msk[ln][i], z);
            }
            h0[(size_t)n * HID_F + o] = z;
            hb[(size_t)n * HID_F + o] =
                __builtin_bit_cast(unsigned short, (__bf16)z);
        }
    }
}

// --------- CSR build, persistent XCD-pinned: count8 / scan / fill8 ---------
// PGRID=1024 blocks, all co-resident at dispatch (4/CU; VGPR 8, no LDS), so
// the initial round-robin blockIdx&7 -> XCD mapping holds for the entire
// kernel.  Partition p = blockIdx&7 owns dst in [p*psz,(p+1)*psz); its 128
// blocks grid-stride the full edge list.
__global__ __launch_bounds__(256) void count8_kernel(
    const int* __restrict__ dst, int* __restrict__ cnt, int E, int psz)
{
    int part = blockIdx.x & (NXCD - 1);
    int q    = blockIdx.x >> 3;                       // 0..127
    int plo = part * psz, phi = plo + psz;
    const int stride = (PGRID >> 3) * 256 * 4;        // 524288 edges
    for (int e0 = (q * 256 + threadIdx.x) * 4; e0 < E; e0 += stride) {
        if (e0 + 3 < E) {
            int4 d4 = *(const int4*)(dst + e0);
            if (d4.x >= plo && d4.x < phi) atomicAdd(&cnt[d4.x], 1);
            if (d4.y >= plo && d4.y < phi) atomicAdd(&cnt[d4.y], 1);
            if (d4.z >= plo && d4.z < phi) atomicAdd(&cnt[d4.z], 1);
            if (d4.w >= plo && d4.w < phi) atomicAdd(&cnt[d4.w], 1);
        } else {
            for (int k = 0; k < 4 && e0 + k < E; ++k) {
                int d = dst[e0 + k];
                if (d >= plo && d < phi) atomicAdd(&cnt[d], 1);
            }
        }
    }
}

__global__ __launch_bounds__(256) void scan1_kernel(
    const int* __restrict__ cnt, int* __restrict__ offs,
    int* __restrict__ bsum, int N)
{
    __shared__ int s[256];
    int base = blockIdx.x * 1024 + threadIdx.x * 4;
    int v0 = (base + 0 < N) ? cnt[base + 0] : 0;
    int v1 = (base + 1 < N) ? cnt[base + 1] : 0;
    int v2 = (base + 2 < N) ? cnt[base + 2] : 0;
    int v3 = (base + 3 < N) ? cnt[base + 3] : 0;
    int tsum = v0 + v1 + v2 + v3;
    s[threadIdx.x] = tsum;
    __syncthreads();
    for (int off = 1; off < 256; off <<= 1) {
        int t = 0;
        if (threadIdx.x >= off) t = s[threadIdx.x - off];
        __syncthreads();
        if (threadIdx.x >= off) s[threadIdx.x] += t;
        __syncthreads();
    }
    int p = s[threadIdx.x] - tsum;
    if (threadIdx.x == 255) bsum[blockIdx.x] = s[255];
    if (base + 0 < N) { offs[base + 0] = p; p += v0; }
    if (base + 1 < N) { offs[base + 1] = p; p += v1; }
    if (base + 2 < N) { offs[base + 2] = p; p += v2; }
    if (base + 3 < N) { offs[base + 3] = p; p += v3; }
}

__global__ __launch_bounds__(256) void scan2_kernel(int* __restrict__ bsum, int nblk)
{
    __shared__ int s[256];
    int v = (threadIdx.x < nblk) ? bsum[threadIdx.x] : 0;
    s[threadIdx.x] = v;
    __syncthreads();
    for (int off = 1; off < 256; off <<= 1) {
        int t = 0;
        if (threadIdx.x >= off) t = s[threadIdx.x - off];
        __syncthreads();
        if (threadIdx.x >= off) s[threadIdx.x] += t;
        __syncthreads();
    }
    if (threadIdx.x < nblk) bsum[threadIdx.x] = s[threadIdx.x] - v;
}

__global__ __launch_bounds__(256) void scan3_kernel(
    int* __restrict__ offs, const int* __restrict__ bsum, int N, int E)
{
    int i = blockIdx.x * 256 + threadIdx.x;
    if (i < N) offs[i] += bsum[i >> 10];
    if (i == 0) offs[N] = E;
}

__global__ __launch_bounds__(256) void fill8_kernel(
    const int* __restrict__ src, const int* __restrict__ dst,
    const int* __restrict__ offs, int* __restrict__ cursor,
    int* __restrict__ csr, int E, int psz)
{
    int part = blockIdx.x & (NXCD - 1);
    int q    = blockIdx.x >> 3;                       // 0..127
    int plo = part * psz, phi = plo + psz;
    const int stride = (PGRID >> 3) * 256 * 4;        // 524288 edges
    for (int e0 = (q * 256 + threadIdx.x) * 4; e0 < E; e0 += stride) {
        if (e0 + 3 < E) {
            int4 d4 = *(const int4*)(dst + e0);
            int4 s4 = *(const int4*)(src + e0);
            if (d4.x >= plo && d4.x < phi) { int p = atomicAdd(&cursor[d4.x], 1); csr[offs[d4.x] + p] = s4.x; }
            if (d4.y >= plo && d4.y < phi) { int p = atomicAdd(&cursor[d4.y], 1); csr[offs[d4.y] + p] = s4.y; }
            if (d4.z >= plo && d4.z < phi) { int p = atomicAdd(&cursor[d4.z], 1); csr[offs[d4.z] + p] = s4.z; }
            if (d4.w >= plo && d4.w < phi) { int p = atomicAdd(&cursor[d4.w], 1); csr[offs[d4.w] + p] = s4.w; }
        } else {
            for (int k = 0; k < 4 && e0 + k < E; ++k) {
                int d = dst[e0 + k];
                if (d >= plo && d < phi) {
                    int p = atomicAdd(&cursor[d], 1);
                    csr[offs[d] + p] = src[e0 + k];
                }
            }
        }
    }
}

// ---------- gather aggregation (bf16 rows): mean over in-neighbors ---------
// one wave per node; lane l owns features [2l, 2l+1] (one dword of hb row)
__global__ __launch_bounds__(256) void agg_kernel(
    const unsigned short* __restrict__ hb, const int* __restrict__ csr,
    const int* __restrict__ offs, unsigned short* __restrict__ meanb, int N)
{
    int wid  = (blockIdx.x * 256 + threadIdx.x) >> 6;   // node id
    int lane = threadIdx.x & 63;
    if (wid >= N) return;
    int lo = offs[wid], hi = offs[wid + 1];
    float ax = 0.f, ay = 0.f;
    for (int base = lo; base < hi; base += 64) {
        int m = hi - base;
        int idx = 0;
        if (lane < m) idx = csr[base + lane];
        int cnt = m < 64 ? m : 64;
        int j = 0;
        for (; j + 3 < cnt; j += 4) {
            int s0 = __shfl(idx, j + 0);
            int s1 = __shfl(idx, j + 1);
            int s2 = __shfl(idx, j + 2);
            int s3 = __shfl(idx, j + 3);
            unsigned int v0 = *(const unsigned int*)(hb + (size_t)s0 * HID_F + lane * 2);
            unsigned int v1 = *(const unsigned int*)(hb + (size_t)s1 * HID_F + lane * 2);
            unsigned int v2 = *(const unsigned int*)(hb + (size_t)s2 * HID_F + lane * 2);
            unsigned int v3 = *(const unsigned int*)(hb + (size_t)s3 * HID_F + lane * 2);
            ax += __builtin_bit_cast(float, v0 << 16) + __builtin_bit_cast(float, v1 << 16)
                + __builtin_bit_cast(float, v2 << 16) + __builtin_bit_cast(float, v3 << 16);
            ay += __builtin_bit_cast(float, v0 & 0xffff0000u) + __builtin_bit_cast(float, v1 & 0xffff0000u)
                + __builtin_bit_cast(float, v2 & 0xffff0000u) + __builtin_bit_cast(float, v3 & 0xffff0000u);
        }
        for (; j < cnt; ++j) {
            int s0 = __shfl(idx, j);
            unsigned int v0 = *(const unsigned int*)(hb + (size_t)s0 * HID_F + lane * 2);
            ax += __builtin_bit_cast(float, v0 << 16);
            ay += __builtin_bit_cast(float, v0 & 0xffff0000u);
        }
    }
    float inv = (hi > lo) ? 1.0f / (float)(hi - lo) : 0.0f;
    unsigned short ux = __builtin_bit_cast(unsigned short, (__bf16)(ax * inv));
    unsigned short uy = __builtin_bit_cast(unsigned short, (__bf16)(ay * inv));
    *(unsigned int*)(meanb + (size_t)wid * HID_F + lane * 2) =
        (unsigned int)ux | ((unsigned int)uy << 16);
}

// -------------------- SAGE update via MFMA ---------------------------------
// z = [hb|meanb](bf16) @ wfrag(bf16, K=256) + bias + hres (fp32); leaky.
__global__ __launch_bounds__(256) void sage_mfma_kernel(
    const unsigned short* __restrict__ hb, const unsigned short* __restrict__ meanb,
    const float* __restrict__ hres, const unsigned short* __restrict__ wfrag,
    const float* __restrict__ bias, float* __restrict__ hout,
    unsigned short* __restrict__ hbout, int N)
{
    int wv = threadIdx.x >> 6;
    int l  = threadIdx.x & 63;
    int n0 = blockIdx.x * 64 + wv * 16;
    int r  = l & 15;
    int kg = l >> 4;                          // 0..3

    const uint4* rowh = (const uint4*)(hb    + (size_t)(n0 + r) * HID_F);
    const uint4* rowm = (const uint4*)(meanb + (size_t)(n0 + r) * HID_F);
    const uint4* wp   = (const uint4*)wfrag + l;

    f32x4 acc[8] = {};
#pragma unroll
    for (int ks = 0; ks < 8; ++ks) {
        uint4 av = (ks < 4) ? rowh[ks * 4 + kg] : rowm[(ks - 4) * 4 + kg];
        bf16x8 a = __builtin_bit_cast(bf16x8, av);
#pragma unroll
        for (int c = 0; c < 8; ++c) {
            uint4 w = wp[(ks * 8 + c) * 64];
            bf16x8 b = __builtin_bit_cast(bf16x8, w);
            acc[c] = __builtin_amdgcn_mfma_f32_16x16x32_bf16(a, b, acc[c], 0, 0, 0);
        }
    }

    // epilogue: D[row=(l>>4)*4+rr][col=c*16+(l&15)]
    int row0 = kg * 4;
#pragma unroll
    for (int c = 0; c < 8; ++c) {
        int col = c * 16 + r;
        float bv = bias[col];
#pragma unroll
        for (int rr = 0; rr < 4; ++rr) {
            int grow = n0 + row0 + rr;
            if (grow < N) {
                float z = acc[c][rr] + bv + hres[(size_t)grow * HID_F + col];
                z = z > 0.f ? z : 0.01f * z;
                hout[(size_t)grow * HID_F + col] = z;
                if (hbout)
                    hbout[(size_t)grow * HID_F + col] =
                        __builtin_bit_cast(unsigned short, (__bf16)z);
            }
        }
    }
}

// ------------- fused graph-mean pool + KAN readout layer 1 ------------------
// 512 threads: 16-row x float4 parallel pooling -> LDS combine -> 128-thread
// KAN epilogue (thread i owns pooled feature i).
__global__ __launch_bounds__(512) void pool_readout1_kernel(
    const float* __restrict__ h, const int* __restrict__ gid,
    const float* __restrict__ coefr1, const float* __restrict__ sbr1,
    const float* __restrict__ ssr1, float* __restrict__ ymid, int N)
{
    int g = blockIdx.x;
    int tid = threadIdx.x;
    __shared__ int s_lo, s_hi;
    if (tid == 0) {
        int lo = 0, hi = N;
        while (lo < hi) { int m = (lo + hi) >> 1; if (gid[m] < g) lo = m + 1; else hi = m; }
        s_lo = lo;
        int lo2 = lo, hi2 = N;
        while (lo2 < hi2) { int m = (lo2 + hi2) >> 1; if (gid[m] < g + 1) lo2 = m + 1; else hi2 = m; }
        s_hi = lo2;
    }
    __syncthreads();
    int lo = s_lo, hi = s_hi;

    // parallel pooling: row-group ro = tid>>5 (16 rows in flight), cols c4..c4+3
    int ro = tid >> 5;
    int c4 = (tid & 31) * 4;
    float4 a = {0.f, 0.f, 0.f, 0.f};
    for (int n = lo + ro; n < hi; n += 16) {
        float4 v = *(const float4*)(h + (size_t)n * HID_F + c4);
        a.x += v.x; a.y += v.y; a.z += v.z; a.w += v.w;
    }
    __shared__ float s_acc[16][HID_F];   // 8 KB
    *(float4*)(&s_acc[ro][c4]) = a;
    __syncthreads();

    // KAN epilogue on first 128 threads (thread i owns feature i)
    __shared__ float s_part[2][MID_F];
    float p[MID_F];
    int i = tid;
    if (tid < HID_F) {
        float acc = 0.f;
#pragma unroll
        for (int r = 0; r < 16; ++r) acc += s_acc[r][i];
        float x = acc * (1.0f / fmaxf((float)(hi - lo), 1.0f));

        float B[NC];
        bspline11(x, B);
        float s = silu_f(x);
        const float* cp  = coefr1 + (size_t)i * (MID_F * NC);
        const float* ssp = ssr1 + (size_t)i * MID_F;
        const float* sbp = sbr1 + (size_t)i * MID_F;
#pragma unroll
        for (int o = 0; o < MID_F; ++o) {
            float t = 0.f;
#pragma unroll
            for (int c = 0; c < NC; ++c) t = fmaf(cp[o * NC + c], B[c], t);
            p[o] = sbp[o] * s + ssp[o] * t;
        }
#pragma unroll
        for (int off = 32; off >= 1; off >>= 1) {
#pragma unroll
            for (int o = 0; o < MID_F; ++o) p[o] += __shfl_down(p[o], off);
        }
        int lane = tid & 63, w = tid >> 6;
        if (lane == 0) {
#pragma unroll
            for (int o = 0; o < MID_F; ++o) s_part[w][o] = p[o];
        }
    }
    __syncthreads();
    if (tid < MID_F)
        ymid[g * MID_F + tid] = s_part[0][tid] + s_part[1][tid];
}

// -------------------- KAN readout layer 2 + sigmoid: [512,5] -> [512,1] ----
__global__ __launch_bounds__(256) void readout2_kernel(
    const float* __restrict__ ymid, const float* __restrict__ coefr2,
    const float* __restrict__ sbr2, const float* __restrict__ ssr2,
    float* __restrict__ out)
{
    int g = blockIdx.x * 256 + threadIdx.x;
    if (g >= NG) return;
    float acc = 0.f;
#pragma unroll
    for (int i = 0; i < MID_F; ++i) {
        float x = ymid[g * MID_F + i];
        float B[NC];
        bspline11(x, B);
        float t = 0.f;
#pragma unroll
        for (int c = 0; c < NC; ++c) t = fmaf(coefr2[i * NC + c], B[c], t);
        acc += sbr2[i] * silu_f(x) + ssr2[i] * t;
    }
    out[g] = 1.0f / (1.0f + expf(-acc));
}

// ---------------------------------------------------------------------------
extern "C" void kernel_launch(void* const* d_in, const int* in_sizes, int n_in,
                              void* d_out, int out_size, void* d_ws, size_t ws_size,
                              hipStream_t stream)
{
    const float* h     = (const float*)d_in[0];
    const int*   src   = (const int*)d_in[1];
    const int*   dst   = (const int*)d_in[2];
    const int*   gid   = (const int*)d_in[3];
    const float* coef1 = (const float*)d_in[4];
    const float* sb1   = (const float*)d_in[5];
    const float* ss1   = (const float*)d_in[6];
    const float* coef2 = (const float*)d_in[7];
    const float* sb2   = (const float*)d_in[8];
    const float* ss2   = (const float*)d_in[9];
    const float* Ws0   = (const float*)d_in[10];
    const float* Wn0   = (const float*)d_in[11];
    const float* b0    = (const float*)d_in[12];
    const float* Ws1   = (const float*)d_in[13];
    const float* Wn1   = (const float*)d_in[14];
    const float* b1    = (const float*)d_in[15];
    const float* coefr1= (const float*)d_in[16];
    const float* sbr1  = (const float*)d_in[17];
    const float* ssr1  = (const float*)d_in[18];
    const float* coefr2= (const float*)d_in[19];
    const float* sbr2  = (const float*)d_in[20];
    const float* ssr2  = (const float*)d_in[21];

    const int N = in_sizes[0] / IN_F;   // 100000
    const int E = in_sizes[1];          // 1600000

    // ---- workspace layout (same total footprint as round 10) ----
    float* ws   = (float*)d_ws;
    float* mid  = ws;                                   // N*5 f32
    float* h0   = mid + (size_t)N * MID_F;              // N*128 f32
    float* h1   = h0 + (size_t)N * HID_F;               // N*128 f32
    unsigned short* meanb = (unsigned short*)(h1 + (size_t)N * HID_F);  // N*128 bf16
    unsigned short* hb    = meanb + (size_t)N * HID_F;                  // N*128 bf16
    float* ymid = (float*)(hb + (size_t)N * HID_F);     // 512*5 f32
    unsigned short* wfrag0 = (unsigned short*)(ymid + NG * MID_F);  // 32768 us
    unsigned short* wfrag1 = wfrag0 + 32768;                        // 32768 us
    int*   cnt  = (int*)(wfrag1 + 32768);               // N (reused as cursor)
    int*   offs = cnt + N;                              // N+1
    int*   bsum = offs + N + 1;                         // 256
    int*   csr  = bsum + 256;                           // E

    // poly tables aliased onto meanb (dead until agg0 writes meanb):
    float* poly1 = (float*)meanb;                       // 64*14*5*4  = 17920 f32
    float* poly2 = poly1 + IN_F * NJ * MID_F * 4;       // 5*14*128*4 = 35840 f32

    const int nblk = (N + 1023) / 1024;
    const int psz  = (N + NXCD - 1) / NXCD;             // 12500

    // build spline polynomial tables + bf16 weight fragment tables
    build_poly1_kernel<<<(IN_F * NJ * MID_F + 255) / 256, 256, 0, stream>>>(coef1, ss1, poly1);
    build_poly2_kernel<<<(MID_F * NJ * HID_F + 255) / 256, 256, 0, stream>>>(coef2, ss2, poly2);
    build_wfrag_kernel<<<(2 * 256 * HID_F + 255) / 256, 256, 0, stream>>>(
        Ws0, Wn0, Ws1, Wn1, wfrag0, wfrag1);

    // KAN encoder
    enc1_kernel<<<(N + 255) / 256, 256, 0, stream>>>(h, poly1, sb1, mid, N);
    enc2_kernel<<<2048, 256, 0, stream>>>(mid, poly2, sb2, h0, hb, N);

    // CSR build (once; reused by both SAGE layers), persistent XCD-pinned
    hipMemsetAsync(cnt, 0, (size_t)N * sizeof(int), stream);
    count8_kernel<<<PGRID, 256, 0, stream>>>(dst, cnt, E, psz);
    scan1_kernel<<<nblk, 256, 0, stream>>>(cnt, offs, bsum, N);
    scan2_kernel<<<1, 256, 0, stream>>>(bsum, nblk);
    scan3_kernel<<<(N + 255) / 256, 256, 0, stream>>>(offs, bsum, N, E);
    hipMemsetAsync(cnt, 0, (size_t)N * sizeof(int), stream);   // cnt -> cursor
    fill8_kernel<<<PGRID, 256, 0, stream>>>(src, dst, offs, cnt, csr, E, psz);

    // SAGE layer 0: agg from hb -> meanb; GEMM; writes h1 + hb (in place)
    agg_kernel<<<(N * 64 + 255) / 256, 256, 0, stream>>>(hb, csr, offs, meanb, N);
    sage_mfma_kernel<<<(N + 63) / 64, 256, 0, stream>>>(
        hb, meanb, h0, wfrag0, b0, h1, hb, N);

    // SAGE layer 1: output bf16 shadow not needed (pool uses fp32)
    agg_kernel<<<(N * 64 + 255) / 256, 256, 0, stream>>>(hb, csr, offs, meanb, N);
    sage_mfma_kernel<<<(N + 63) / 64, 256, 0, stream>>>(
        hb, meanb, h1, wfrag1, b1, h0, (unsigned short*)nullptr, N);

    // fused pool + readout
    pool_readout1_kernel<<<NG, 512, 0, stream>>>(h0, gid, coefr1, sbr1, ssr1, ymid, N);
    readout2_kernel<<<2, 256, 0, stream>>>(ymid, coefr2, sbr2, ssr2, (float*)d_out);
}

// Round 15
// 556.471 us; speedup vs baseline: 1.0666x; 1.0600x over previous
//
#include <hip/hip_runtime.h>

// ---------------------------------------------------------------------------
// KAN-GNN forward on MI355X.  Sizes (fixed by reference): N=100000 nodes,
// E=1600000 edges, IN=64, MID=5, HID=128, OUT=1, NG=512 graphs, C=11 basis.
// Round 15: full-bf16 node state.  Three fill theories falsified (write amp
// is structural: coherent atomics + long-lived csr lines, random edge order)
// -> accept fill; instead cut the BW-bound sage path: drop fp32 h0/h1
// entirely (residual read from hb, in-place hb update; pool reads bf16).
// sage traffic 180->77MB/layer.  Extras: fill cursor = atomicSub countdown
// on cnt (removes 2nd memset), agg unroll 4->8 (latency hiding).
// ---------------------------------------------------------------------------

#define IN_F   64
#define MID_F  5
#define HID_F  128
#define NG     512
#define NC     11   // G_GRID + K_SPLINE = 8 + 3
#define NJ     14   // intervals of [-1.75, 1.75) at h=0.25
#define NXCD   8
#define PGRID  1024  // persistent blocks for CSR build

typedef __attribute__((ext_vector_type(8))) __bf16 bf16x8;
typedef __attribute__((ext_vector_type(4))) float  f32x4;

__device__ __forceinline__ float bf2f(unsigned short u) {
    return __builtin_bit_cast(float, ((unsigned int)u) << 16);
}

// Cubic B-spline basis on uniform knots t_j = -1.75 + 0.25 j, j=0..14.
__device__ __forceinline__ void bspline11(float x, float* __restrict__ B) {
    float b[14];
#pragma unroll
    for (int j = 0; j < 14; ++j) {
        float tj = -1.75f + 0.25f * j;
        b[j] = (x >= tj && x < tj + 0.25f) ? 1.0f : 0.0f;
    }
#pragma unroll
    for (int d = 1; d <= 3; ++d) {
        float inv = 1.0f / (0.25f * d);
#pragma unroll 14
        for (int j = 0; j < 14 - 3; ++j) {
            if (j < 14 - d) {
                float tj   = -1.75f + 0.25f * j;
                float tjd1 = tj + 0.25f * (d + 1);
                b[j] = ((x - tj) * b[j] + (tjd1 - x) * b[j + 1]) * inv;
            }
        }
        if (d < 3) {
#pragma unroll
            for (int j = 11; j < 14; ++j) {
                if (j < 14 - d) {
                    float tj   = -1.75f + 0.25f * j;
                    float tjd1 = tj + 0.25f * (d + 1);
                    b[j] = ((x - tj) * b[j] + (tjd1 - x) * b[j + 1]) * inv;
                }
            }
        }
    }
#pragma unroll
    for (int j = 0; j < NC; ++j) B[j] = b[j];
}

__device__ __forceinline__ float silu_f(float x) { return x / (1.0f + expf(-x)); }

// ---- build piecewise-cubic tables: poly[idx][4] = {a,b,c,d} in local u ----
__device__ __forceinline__ float4 poly_from_coefs(float c0, float c1, float c2, float c3) {
    const float s = 1.0f / 6.0f;
    float4 p;
    p.x = (-c0 + 3.f*c1 - 3.f*c2 + c3) * s;   // u^3
    p.y = ( 3.f*c0 - 6.f*c1 + 3.f*c2) * s;    // u^2
    p.z = (-3.f*c0 + 3.f*c2) * s;             // u^1
    p.w = (      c0 + 4.f*c1 + c2) * s;       // 1
    return p;
}

// poly1 layout: [i (64)][j (14)][o (5)][4]
__global__ __launch_bounds__(256) void build_poly1_kernel(
    const float* __restrict__ coef1, const float* __restrict__ ss1,
    float* __restrict__ poly1)
{
    int idx = blockIdx.x * 256 + threadIdx.x;
    if (idx >= IN_F * NJ * MID_F) return;
    int o = idx % MID_F;
    int t = idx / MID_F;
    int j = t % NJ;
    int i = t / NJ;
    float ss = ss1[i * MID_F + o];
    float c[4];
#pragma unroll
    for (int k = 0; k < 4; ++k) {
        int cc = j - 3 + k;
        c[k] = (cc >= 0 && cc <= 10) ? coef1[(i * MID_F + o) * NC + cc] * ss : 0.f;
    }
    *(float4*)(poly1 + (size_t)idx * 4) = poly_from_coefs(c[0], c[1], c[2], c[3]);
}

// poly2 layout: [i (5)][j (14)][o (128)][4]
__global__ __launch_bounds__(256) void build_poly2_kernel(
    const float* __restrict__ coef2, const float* __restrict__ ss2,
    float* __restrict__ poly2)
{
    int idx = blockIdx.x * 256 + threadIdx.x;
    if (idx >= MID_F * NJ * HID_F) return;
    int o = idx & 127;
    int t = idx >> 7;
    int j = t % NJ;
    int i = t / NJ;
    float ss = ss2[i * HID_F + o];
    float c[4];
#pragma unroll
    for (int k = 0; k < 4; ++k) {
        int cc = j - 3 + k;
        c[k] = (cc >= 0 && cc <= 10) ? coef2[(i * HID_F + o) * NC + cc] * ss : 0.f;
    }
    *(float4*)(poly2 + (size_t)idx * 4) = poly_from_coefs(c[0], c[1], c[2], c[3]);
}

// ---- repack [Ws;Wn] (K=256 x 128) into MFMA fragment order, bf16 ----------
__global__ __launch_bounds__(256) void build_wfrag_kernel(
    const float* __restrict__ Ws0, const float* __restrict__ Wn0,
    const float* __restrict__ Ws1, const float* __restrict__ Wn1,
    unsigned short* __restrict__ wfrag0, unsigned short* __restrict__ wfrag1)
{
    int t = blockIdx.x * 256 + threadIdx.x;
    if (t >= 2 * 256 * HID_F) return;
    int layer = t >> 15;
    int e = t & 32767;
    int col = e & 127;
    int k   = e >> 7;          // 0..255
    int ks  = k >> 5;
    int kin = k & 31;
    int lg  = kin >> 3;
    int j   = kin & 7;
    int c   = col >> 4;
    int li  = col & 15;
    int l   = lg * 16 + li;
    const float* Ws = layer ? Ws1 : Ws0;
    const float* Wn = layer ? Wn1 : Wn0;
    float v = (k < HID_F) ? Ws[k * HID_F + col] : Wn[(k - HID_F) * HID_F + col];
    unsigned short us = __builtin_bit_cast(unsigned short, (__bf16)v);
    unsigned short* dst = layer ? wfrag1 : wfrag0;
    dst[((ks * 8 + c) * 64 + l) * 8 + j] = us;
}

// -------------------- KAN encoder layer 1: [N,64] -> [N,5] -----------------
__global__ __launch_bounds__(256) void enc1_kernel(
    const float* __restrict__ h, const float* __restrict__ poly1,
    const float* __restrict__ sb1, float* __restrict__ mid, int N)
{
    __shared__ float s_sb[IN_F * MID_F];
    for (int idx = threadIdx.x; idx < IN_F * MID_F; idx += 256)
        s_sb[idx] = sb1[idx];
    __syncthreads();

    int n = blockIdx.x * 256 + threadIdx.x;
    if (n >= N) return;
    const float* hr = h + (size_t)n * IN_F;
    float acc[MID_F] = {0, 0, 0, 0, 0};

#pragma unroll 4
    for (int i4 = 0; i4 < IN_F; i4 += 4) {
        float4 xv = *(const float4*)(hr + i4);
        float xs[4] = {xv.x, xv.y, xv.z, xv.w};
#pragma unroll
        for (int k = 0; k < 4; ++k) {
            int i = i4 + k;
            float x = xs[k];
            float xf = (x + 1.75f) * 4.0f;
            float fj = floorf(xf);
            int j0 = (int)fj;
            j0 = j0 < 0 ? 0 : (j0 > 13 ? 13 : j0);
            float u = xf - fj;
            float msk = (x >= -1.75f && x < 1.75f) ? 1.0f : 0.0f;
            float s = silu_f(x);
            const float* pp = poly1 + ((size_t)(i * NJ + j0) * MID_F) * 4;
#pragma unroll
            for (int o = 0; o < MID_F; ++o) {
                float4 p = *(const float4*)(pp + 4 * o);
                float t = fmaf(fmaf(fmaf(p.x, u, p.y), u, p.z), u, p.w);
                acc[o] = fmaf(s_sb[i * MID_F + o], s, acc[o]);
                acc[o] = fmaf(t, msk, acc[o]);
            }
        }
    }
#pragma unroll
    for (int o = 0; o < MID_F; ++o) mid[(size_t)n * MID_F + o] = acc[o];
}

// ------------- KAN encoder layer 2: [N,5] -> [N,128] bf16 ------------------
__global__ __launch_bounds__(256) void enc2_kernel(
    const float* __restrict__ mid, const float* __restrict__ poly2,
    const float* __restrict__ sb2, unsigned short* __restrict__ hb, int N)
{
    __shared__ float s_u[2][MID_F], s_sil[2][MID_F], s_msk[2][MID_F];
    __shared__ int   s_j0[2][MID_F];
    int o  = threadIdx.x & 127;
    int ln = threadIdx.x >> 7;

    float sbr[MID_F];
#pragma unroll
    for (int i = 0; i < MID_F; ++i) sbr[i] = sb2[i * HID_F + o];

    int nTiles = (N + 1) / 2;
    for (int tile = blockIdx.x; tile < nTiles; tile += gridDim.x) {
        __syncthreads();
        if (threadIdx.x < 2 * MID_F) {
            int l = threadIdx.x / MID_F, i = threadIdx.x % MID_F;
            int n = tile * 2 + l;
            float x = (n < N) ? mid[(size_t)n * MID_F + i] : 0.f;
            float xf = (x + 1.75f) * 4.0f;
            float fj = floorf(xf);
            int j0 = (int)fj;
            j0 = j0 < 0 ? 0 : (j0 > 13 ? 13 : j0);
            s_j0[l][i]  = j0;
            s_u[l][i]   = xf - fj;
            s_msk[l][i] = (x >= -1.75f && x < 1.75f) ? 1.0f : 0.0f;
            s_sil[l][i] = silu_f(x);
        }
        __syncthreads();
        int n = tile * 2 + ln;
        if (n < N) {
            float z = 0.f;
#pragma unroll
            for (int i = 0; i < MID_F; ++i) {
                float4 p = *(const float4*)(poly2 +
                            ((size_t)((i * NJ + s_j0[ln][i]) * HID_F + o)) * 4);
                float u = s_u[ln][i];
                float t = fmaf(fmaf(fmaf(p.x, u, p.y), u, p.z), u, p.w);
                z = fmaf(sbr[i], s_sil[ln][i], z);
                z = fmaf(t, s_msk[ln][i], z);
            }
            hb[(size_t)n * HID_F + o] =
                __builtin_bit_cast(unsigned short, (__bf16)z);
        }
    }
}

// --------- CSR build, persistent XCD-partitioned: count8 / scan / fill8 ----
__global__ __launch_bounds__(256) void count8_kernel(
    const int* __restrict__ dst, int* __restrict__ cnt, int E, int psz)
{
    int part = blockIdx.x & (NXCD - 1);
    int q    = blockIdx.x >> 3;                       // 0..127
    int plo = part * psz, phi = plo + psz;
    const int stride = (PGRID >> 3) * 256 * 4;        // 524288 edges
    for (int e0 = (q * 256 + threadIdx.x) * 4; e0 < E; e0 += stride) {
        if (e0 + 3 < E) {
            int4 d4 = *(const int4*)(dst + e0);
            if (d4.x >= plo && d4.x < phi) atomicAdd(&cnt[d4.x], 1);
            if (d4.y >= plo && d4.y < phi) atomicAdd(&cnt[d4.y], 1);
            if (d4.z >= plo && d4.z < phi) atomicAdd(&cnt[d4.z], 1);
            if (d4.w >= plo && d4.w < phi) atomicAdd(&cnt[d4.w], 1);
        } else {
            for (int k = 0; k < 4 && e0 + k < E; ++k) {
                int d = dst[e0 + k];
                if (d >= plo && d < phi) atomicAdd(&cnt[d], 1);
            }
        }
    }
}

__global__ __launch_bounds__(256) void scan1_kernel(
    const int* __restrict__ cnt, int* __restrict__ offs,
    int* __restrict__ bsum, int N)
{
    __shared__ int s[256];
    int base = blockIdx.x * 1024 + threadIdx.x * 4;
    int v0 = (base + 0 < N) ? cnt[base + 0] : 0;
    int v1 = (base + 1 < N) ? cnt[base + 1] : 0;
    int v2 = (base + 2 < N) ? cnt[base + 2] : 0;
    int v3 = (base + 3 < N) ? cnt[base + 3] : 0;
    int tsum = v0 + v1 + v2 + v3;
    s[threadIdx.x] = tsum;
    __syncthreads();
    for (int off = 1; off < 256; off <<= 1) {
        int t = 0;
        if (threadIdx.x >= off) t = s[threadIdx.x - off];
        __syncthreads();
        if (threadIdx.x >= off) s[threadIdx.x] += t;
        __syncthreads();
    }
    int p = s[threadIdx.x] - tsum;
    if (threadIdx.x == 255) bsum[blockIdx.x] = s[255];
    if (base + 0 < N) { offs[base + 0] = p; p += v0; }
    if (base + 1 < N) { offs[base + 1] = p; p += v1; }
    if (base + 2 < N) { offs[base + 2] = p; p += v2; }
    if (base + 3 < N) { offs[base + 3] = p; p += v3; }
}

__global__ __launch_bounds__(256) void scan2_kernel(int* __restrict__ bsum, int nblk)
{
    __shared__ int s[256];
    int v = (threadIdx.x < nblk) ? bsum[threadIdx.x] : 0;
    s[threadIdx.x] = v;
    __syncthreads();
    for (int off = 1; off < 256; off <<= 1) {
        int t = 0;
        if (threadIdx.x >= off) t = s[threadIdx.x - off];
        __syncthreads();
        if (threadIdx.x >= off) s[threadIdx.x] += t;
        __syncthreads();
    }
    if (threadIdx.x < nblk) bsum[threadIdx.x] = s[threadIdx.x] - v;
}

__global__ __launch_bounds__(256) void scan3_kernel(
    int* __restrict__ offs, const int* __restrict__ bsum, int N, int E)
{
    int i = blockIdx.x * 256 + threadIdx.x;
    if (i < N) offs[i] += bsum[i >> 10];
    if (i == 0) offs[N] = E;
}

// fill with countdown cursor: cnt still holds degrees after scan; slot =
// offs[d] + (atomicSub(cnt[d])-1).  No second memset; order within a dst is
// arbitrary (mean is order-independent up to fp rounding).
__global__ __launch_bounds__(256) void fill8_kernel(
    const int* __restrict__ src, const int* __restrict__ dst,
    const int* __restrict__ offs, int* __restrict__ cnt,
    int* __restrict__ csr, int E, int psz)
{
    int part = blockIdx.x & (NXCD - 1);
    int q    = blockIdx.x >> 3;                       // 0..127
    int plo = part * psz, phi = plo + psz;
    const int stride = (PGRID >> 3) * 256 * 4;        // 524288 edges
    for (int e0 = (q * 256 + threadIdx.x) * 4; e0 < E; e0 += stride) {
        if (e0 + 3 < E) {
            int4 d4 = *(const int4*)(dst + e0);
            int4 s4 = *(const int4*)(src + e0);
            if (d4.x >= plo && d4.x < phi) { int p = atomicSub(&cnt[d4.x], 1) - 1; csr[offs[d4.x] + p] = s4.x; }
            if (d4.y >= plo && d4.y < phi) { int p = atomicSub(&cnt[d4.y], 1) - 1; csr[offs[d4.y] + p] = s4.y; }
            if (d4.z >= plo && d4.z < phi) { int p = atomicSub(&cnt[d4.z], 1) - 1; csr[offs[d4.z] + p] = s4.z; }
            if (d4.w >= plo && d4.w < phi) { int p = atomicSub(&cnt[d4.w], 1) - 1; csr[offs[d4.w] + p] = s4.w; }
        } else {
            for (int k = 0; k < 4 && e0 + k < E; ++k) {
                int d = dst[e0 + k];
                if (d >= plo && d < phi) {
                    int p = atomicSub(&cnt[d], 1) - 1;
                    csr[offs[d] + p] = src[e0 + k];
                }
            }
        }
    }
}

// ---------- gather aggregation (bf16 rows): mean over in-neighbors ---------
// one wave per node; lane l owns features [2l, 2l+1]; 8-deep load unroll.
__global__ __launch_bounds__(256) void agg_kernel(
    const unsigned short* __restrict__ hb, const int* __restrict__ csr,
    const int* __restrict__ offs, unsigned short* __restrict__ meanb, int N)
{
    int wid  = (blockIdx.x * 256 + threadIdx.x) >> 6;   // node id
    int lane = threadIdx.x & 63;
    if (wid >= N) return;
    int lo = offs[wid], hi = offs[wid + 1];
    float ax = 0.f, ay = 0.f;
    for (int base = lo; base < hi; base += 64) {
        int m = hi - base;
        int idx = 0;
        if (lane < m) idx = csr[base + lane];
        int cnt = m < 64 ? m : 64;
        int j = 0;
        for (; j + 7 < cnt; j += 8) {
            unsigned int v[8];
#pragma unroll
            for (int k = 0; k < 8; ++k) {
                int s = __shfl(idx, j + k);
                v[k] = *(const unsigned int*)(hb + (size_t)s * HID_F + lane * 2);
            }
#pragma unroll
            for (int k = 0; k < 8; ++k) {
                ax += __builtin_bit_cast(float, v[k] << 16);
                ay += __builtin_bit_cast(float, v[k] & 0xffff0000u);
            }
        }
        for (; j < cnt; ++j) {
            int s0 = __shfl(idx, j);
            unsigned int v0 = *(const unsigned int*)(hb + (size_t)s0 * HID_F + lane * 2);
            ax += __builtin_bit_cast(float, v0 << 16);
            ay += __builtin_bit_cast(float, v0 & 0xffff0000u);
        }
    }
    float inv = (hi > lo) ? 1.0f / (float)(hi - lo) : 0.0f;
    unsigned short ux = __builtin_bit_cast(unsigned short, (__bf16)(ax * inv));
    unsigned short uy = __builtin_bit_cast(unsigned short, (__bf16)(ay * inv));
    *(unsigned int*)(meanb + (size_t)wid * HID_F + lane * 2) =
        (unsigned int)ux | ((unsigned int)uy << 16);
}

// -------------------- SAGE update via MFMA, full-bf16 state ----------------
// z = [hb|meanb](bf16) @ wfrag(bf16, K=256) + bias + bf2f(hb); leaky;
// hb updated IN PLACE (each block reads only its own 64 rows before writing).
__global__ __launch_bounds__(256) void sage_mfma_kernel(
    unsigned short* __restrict__ hb, const unsigned short* __restrict__ meanb,
    const unsigned short* __restrict__ wfrag, const float* __restrict__ bias,
    int N)
{
    int wv = threadIdx.x >> 6;
    int l  = threadIdx.x & 63;
    int n0 = blockIdx.x * 64 + wv * 16;
    int r  = l & 15;
    int kg = l >> 4;                          // 0..3

    const uint4* rowh = (const uint4*)(hb    + (size_t)(n0 + r) * HID_F);
    const uint4* rowm = (const uint4*)(meanb + (size_t)(n0 + r) * HID_F);
    const uint4* wp   = (const uint4*)wfrag + l;

    f32x4 acc[8] = {};
#pragma unroll
    for (int ks = 0; ks < 8; ++ks) {
        uint4 av = (ks < 4) ? rowh[ks * 4 + kg] : rowm[(ks - 4) * 4 + kg];
        bf16x8 a = __builtin_bit_cast(bf16x8, av);
#pragma unroll
        for (int c = 0; c < 8; ++c) {
            uint4 w = wp[(ks * 8 + c) * 64];
            bf16x8 b = __builtin_bit_cast(bf16x8, w);
            acc[c] = __builtin_amdgcn_mfma_f32_16x16x32_bf16(a, b, acc[c], 0, 0, 0);
        }
    }

    // epilogue: D[row=(l>>4)*4+rr][col=c*16+(l&15)]; residual read then
    // same-address write (same thread) -> in-place safe.
    int row0 = kg * 4;
#pragma unroll
    for (int c = 0; c < 8; ++c) {
        int col = c * 16 + r;
        float bv = bias[col];
#pragma unroll
        for (int rr = 0; rr < 4; ++rr) {
            int grow = n0 + row0 + rr;
            if (grow < N) {
                size_t off = (size_t)grow * HID_F + col;
                float z = acc[c][rr] + bv + bf2f(hb[off]);
                z = z > 0.f ? z : 0.01f * z;
                hb[off] = __builtin_bit_cast(unsigned short, (__bf16)z);
            }
        }
    }
}

// ------------- fused graph-mean pool + KAN readout layer 1 (bf16 in) -------
__global__ __launch_bounds__(512) void pool_readout1_kernel(
    const unsigned short* __restrict__ hb, const int* __restrict__ gid,
    const float* __restrict__ coefr1, const float* __restrict__ sbr1,
    const float* __restrict__ ssr1, float* __restrict__ ymid, int N)
{
    int g = blockIdx.x;
    int tid = threadIdx.x;
    __shared__ int s_lo, s_hi;
    if (tid == 0) {
        int lo = 0, hi = N;
        while (lo < hi) { int m = (lo + hi) >> 1; if (gid[m] < g) lo = m + 1; else hi = m; }
        s_lo = lo;
        int lo2 = lo, hi2 = N;
        while (lo2 < hi2) { int m = (lo2 + hi2) >> 1; if (gid[m] < g + 1) lo2 = m + 1; else hi2 = m; }
        s_hi = lo2;
    }
    __syncthreads();
    int lo = s_lo, hi = s_hi;

    // parallel pooling: row-group ro = tid>>5 (16 rows), cols c4..c4+3 (bf16x4)
    int ro = tid >> 5;
    int c4 = (tid & 31) * 4;
    float a0 = 0.f, a1 = 0.f, a2 = 0.f, a3 = 0.f;
    for (int n = lo + ro; n < hi; n += 16) {
        uint2 v = *(const uint2*)(hb + (size_t)n * HID_F + c4);
        a0 += __builtin_bit_cast(float, v.x << 16);
        a1 += __builtin_bit_cast(float, v.x & 0xffff0000u);
        a2 += __builtin_bit_cast(float, v.y << 16);
        a3 += __builtin_bit_cast(float, v.y & 0xffff0000u);
    }
    __shared__ float s_acc[16][HID_F];   // 8 KB
    s_acc[ro][c4 + 0] = a0;
    s_acc[ro][c4 + 1] = a1;
    s_acc[ro][c4 + 2] = a2;
    s_acc[ro][c4 + 3] = a3;
    __syncthreads();

    // KAN epilogue on first 128 threads (thread i owns feature i)
    __shared__ float s_part[2][MID_F];
    float p[MID_F];
    int i = tid;
    if (tid < HID_F) {
        float acc = 0.f;
#pragma unroll
        for (int r = 0; r < 16; ++r) acc += s_acc[r][i];
        float x = acc * (1.0f / fmaxf((float)(hi - lo), 1.0f));

        float B[NC];
        bspline11(x, B);
        float s = silu_f(x);
        const float* cp  = coefr1 + (size_t)i * (MID_F * NC);
        const float* ssp = ssr1 + (size_t)i * MID_F;
        const float* sbp = sbr1 + (size_t)i * MID_F;
#pragma unroll
        for (int o = 0; o < MID_F; ++o) {
            float t = 0.f;
#pragma unroll
            for (int c = 0; c < NC; ++c) t = fmaf(cp[o * NC + c], B[c], t);
            p[o] = sbp[o] * s + ssp[o] * t;
        }
#pragma unroll
        for (int off = 32; off >= 1; off >>= 1) {
#pragma unroll
            for (int o = 0; o < MID_F; ++o) p[o] += __shfl_down(p[o], off);
        }
        int lane = tid & 63, w = tid >> 6;
        if (lane == 0) {
#pragma unroll
            for (int o = 0; o < MID_F; ++o) s_part[w][o] = p[o];
        }
    }
    __syncthreads();
    if (tid < MID_F)
        ymid[g * MID_F + tid] = s_part[0][tid] + s_part[1][tid];
}

// -------------------- KAN readout layer 2 + sigmoid: [512,5] -> [512,1] ----
__global__ __launch_bounds__(256) void readout2_kernel(
    const float* __restrict__ ymid, const float* __restrict__ coefr2,
    const float* __restrict__ sbr2, const float* __restrict__ ssr2,
    float* __restrict__ out)
{
    int g = blockIdx.x * 256 + threadIdx.x;
    if (g >= NG) return;
    float acc = 0.f;
#pragma unroll
    for (int i = 0; i < MID_F; ++i) {
        float x = ymid[g * MID_F + i];
        float B[NC];
        bspline11(x, B);
        float t = 0.f;
#pragma unroll
        for (int c = 0; c < NC; ++c) t = fmaf(coefr2[i * NC + c], B[c], t);
        acc += sbr2[i] * silu_f(x) + ssr2[i] * t;
    }
    out[g] = 1.0f / (1.0f + expf(-acc));
}

// ---------------------------------------------------------------------------
extern "C" void kernel_launch(void* const* d_in, const int* in_sizes, int n_in,
                              void* d_out, int out_size, void* d_ws, size_t ws_size,
                              hipStream_t stream)
{
    const float* h     = (const float*)d_in[0];
    const int*   src   = (const int*)d_in[1];
    const int*   dst   = (const int*)d_in[2];
    const int*   gid   = (const int*)d_in[3];
    const float* coef1 = (const float*)d_in[4];
    const float* sb1   = (const float*)d_in[5];
    const float* ss1   = (const float*)d_in[6];
    const float* coef2 = (const float*)d_in[7];
    const float* sb2   = (const float*)d_in[8];
    const float* ss2   = (const float*)d_in[9];
    const float* Ws0   = (const float*)d_in[10];
    const float* Wn0   = (const float*)d_in[11];
    const float* b0    = (const float*)d_in[12];
    const float* Ws1   = (const float*)d_in[13];
    const float* Wn1   = (const float*)d_in[14];
    const float* b1    = (const float*)d_in[15];
    const float* coefr1= (const float*)d_in[16];
    const float* sbr1  = (const float*)d_in[17];
    const float* ssr1  = (const float*)d_in[18];
    const float* coefr2= (const float*)d_in[19];
    const float* sbr2  = (const float*)d_in[20];
    const float* ssr2  = (const float*)d_in[21];

    const int N = in_sizes[0] / IN_F;   // 100000
    const int E = in_sizes[1];          // 1600000

    // ---- workspace layout (h0/h1 fp32 buffers removed) ----
    float* ws   = (float*)d_ws;
    float* mid  = ws;                                   // N*5 f32
    unsigned short* meanb = (unsigned short*)(mid + (size_t)N * MID_F);  // N*128 bf16
    unsigned short* hb    = meanb + (size_t)N * HID_F;                   // N*128 bf16
    float* ymid = (float*)(hb + (size_t)N * HID_F);     // 512*5 f32
    unsigned short* wfrag0 = (unsigned short*)(ymid + NG * MID_F);  // 32768 us
    unsigned short* wfrag1 = wfrag0 + 32768;                        // 32768 us
    int*   cnt  = (int*)(wfrag1 + 32768);               // N (degree/cursor)
    int*   offs = cnt + N;                              // N+1
    int*   bsum = offs + N + 1;                         // 256
    int*   csr  = bsum + 256;                           // E

    // poly tables aliased onto meanb (dead until agg0 writes meanb):
    float* poly1 = (float*)meanb;                       // 64*14*5*4  = 17920 f32
    float* poly2 = poly1 + IN_F * NJ * MID_F * 4;       // 5*14*128*4 = 35840 f32

    const int nblk = (N + 1023) / 1024;
    const int psz  = (N + NXCD - 1) / NXCD;             // 12500

    // build spline polynomial tables + bf16 weight fragment tables
    build_poly1_kernel<<<(IN_F * NJ * MID_F + 255) / 256, 256, 0, stream>>>(coef1, ss1, poly1);
    build_poly2_kernel<<<(MID_F * NJ * HID_F + 255) / 256, 256, 0, stream>>>(coef2, ss2, poly2);
    build_wfrag_kernel<<<(2 * 256 * HID_F + 255) / 256, 256, 0, stream>>>(
        Ws0, Wn0, Ws1, Wn1, wfrag0, wfrag1);

    // KAN encoder
    enc1_kernel<<<(N + 255) / 256, 256, 0, stream>>>(h, poly1, sb1, mid, N);
    enc2_kernel<<<2048, 256, 0, stream>>>(mid, poly2, sb2, hb, N);

    // CSR build (once; reused by both SAGE layers)
    hipMemsetAsync(cnt, 0, (size_t)N * sizeof(int), stream);
    count8_kernel<<<PGRID, 256, 0, stream>>>(dst, cnt, E, psz);
    scan1_kernel<<<nblk, 256, 0, stream>>>(cnt, offs, bsum, N);
    scan2_kernel<<<1, 256, 0, stream>>>(bsum, nblk);
    scan3_kernel<<<(N + 255) / 256, 256, 0, stream>>>(offs, bsum, N, E);
    fill8_kernel<<<PGRID, 256, 0, stream>>>(src, dst, offs, cnt, csr, E, psz);

    // SAGE layer 0 (hb updated in place)
    agg_kernel<<<(N * 64 + 255) / 256, 256, 0, stream>>>(hb, csr, offs, meanb, N);
    sage_mfma_kernel<<<(N + 63) / 64, 256, 0, stream>>>(hb, meanb, wfrag0, b0, N);

    // SAGE layer 1
    agg_kernel<<<(N * 64 + 255) / 256, 256, 0, stream>>>(hb, csr, offs, meanb, N);
    sage_mfma_kernel<<<(N + 63) / 64, 256, 0, stream>>>(hb, meanb, wfrag1, b1, N);

    // fused pool + readout
    pool_readout1_kernel<<<NG, 512, 0, stream>>>(hb, gid, coefr1, sbr1, ssr1, ymid, N);
    readout2_kernel<<<2, 256, 0, stream>>>(ymid, coefr2, sbr2, ssr2, (float*)d_out);
}